// Round 7
// baseline (3575.537 us; speedup 1.0000x reference)
//
#include <hip/hip_runtime.h>
#include <math.h>

static constexpr int H = 496, W = 432, Bn = 2, Np = 16000;
static constexpr int HW = H * W;  // 214272

// Gold-matching binning: XLA strength-reduces divide-by-constant to multiply by
// the f32-rounded reciprocal. RN_f32(1/0.16f) == 6.25f exactly, so the gold
// quotient is px * 6.25f (differs from IEEE px/0.16f by <=1 ulp -> O(1) boundary
// points out of 32k flip bins; this was the residual 0.2676 error).
__device__ inline void bin_xy(float px, float py, int& ix, int& iy) {
  ix = (int)floorf(px * 6.25f);
  iy = (int)floorf((py + 39.68f) * 6.25f);
  ix = min(max(ix, 0), W - 1);
  iy = min(max(iy, 0), H - 1);
}

// ---------------- Voxelization pass 1: per-pillar count + xyz sums ----------------
__global__ __launch_bounds__(256)
void count_kernel(const float* __restrict__ pts, int* __restrict__ cnt,
                  float* __restrict__ sums) {
  int p = blockIdx.x * blockDim.x + threadIdx.x;
  if (p >= Bn * Np) return;
  float px = pts[p * 4 + 0], py = pts[p * 4 + 1], pz = pts[p * 4 + 2];
  int b = p / Np;
  int ix, iy;
  bin_xy(px, py, ix, iy);
  int gid = b * HW + iy * W + ix;
  atomicAdd(&cnt[gid], 1);
  atomicAdd(&sums[3 * gid + 0], px);
  atomicAdd(&sums[3 * gid + 1], py);
  atomicAdd(&sums[3 * gid + 2], pz);
}

// ------------- Voxelization pass 2: VFE linear+BN+relu, atomicMax scatter -------------
// Canvas lives in d_out channels 20..83 (batch stride 84*HW): consumed by
// block1-conv0, later overwritten by block3 ping-pong, finally holds x3.
__global__ __launch_bounds__(256)
void vfe_kernel(const float* __restrict__ pts, const int* __restrict__ cnt,
                const float* __restrict__ sums, const float* __restrict__ vw,
                const float* __restrict__ vs, const float* __restrict__ vt,
                float* __restrict__ out) {
  int tid = blockIdx.x * blockDim.x + threadIdx.x;
  if (tid >= Bn * Np * 64) return;
  int o = tid & 63;
  int p = tid >> 6;
  int b = p / Np;
  float px = pts[p * 4 + 0], py = pts[p * 4 + 1];
  float pz = pts[p * 4 + 2], pr = pts[p * 4 + 3];
  int ix, iy;
  bin_xy(px, py, ix, iy);
  int gid = b * HW + iy * W + ix;
  int n = cnt[gid];
  float denom = (float)max(n, 1);
  float mx = sums[3 * gid + 0] / denom;
  float my = sums[3 * gid + 1] / denom;
  float mz = sums[3 * gid + 2] / denom;
  // center = cid*vox + (vox*0.5 + pc_min) in fp32; z-center exactly -1.0
  float cx = (float)ix * 0.16f + 0.08f;
  float cy = (float)iy * 0.16f + (0.08f - 39.68f);
  float f[10] = {px, py, pz, pr, px - mx, py - my, pz - mz,
                 px - cx, py - cy, pz + 1.0f};
  const float* wr = vw + o * 10;
  float d = 0.f;
#pragma unroll
  for (int c = 0; c < 10; c++) d += f[c] * wr[c];
  float val = d * vs[o] + vt[o];
  val = fmaxf(val, 0.f);
  // reference maxes over all 32 slots; slots >= n contribute relu(t[o])
  if (n < 32) val = fmaxf(val, fmaxf(vt[o], 0.f));
  unsigned int* dst = (unsigned int*)(out + (size_t)b * (84 * HW) +
                                      (size_t)(20 + o) * HW + (size_t)iy * W + ix);
  atomicMax(dst, __float_as_uint(val));  // vals >= 0, init 0: uint order == float order
}

// ---------------- Direct 3x3 conv + BN + relu (NCHW, pad 1, stride 1) ----------------
// npix = number of pixels covered (HW for single-batch launch, 2*HW for both).
template <int CI, int COT>
__global__ __launch_bounds__(256)
void conv3x3(const float* __restrict__ in, int in_bs, const float* __restrict__ w,
             const float* __restrict__ s, const float* __restrict__ t,
             float* __restrict__ out, int out_bs, int npix) {
  int pix = blockIdx.x * blockDim.x + threadIdx.x;
  if (pix >= npix) return;
  int b = pix / HW;
  int rem = pix - b * HW;
  int y = rem / W;
  int x = rem - y * W;
  int co0 = blockIdx.y * COT;
  const float* inb = in + (size_t)b * in_bs;

  int offs[9];
  bool okm[9];
#pragma unroll
  for (int ky = 0; ky < 3; ky++) {
    int yy = y + ky - 1;
    bool yok = (unsigned)yy < (unsigned)H;
#pragma unroll
    for (int kx = 0; kx < 3; kx++) {
      int xx = x + kx - 1;
      okm[ky * 3 + kx] = yok && ((unsigned)xx < (unsigned)W);
      offs[ky * 3 + kx] = yy * W + xx;
    }
  }

  float acc[COT];
#pragma unroll
  for (int i = 0; i < COT; i++) acc[i] = 0.f;

  for (int ci = 0; ci < CI; ci++) {
    const float* ip = inb + (size_t)ci * HW;
    float iv[9];
#pragma unroll
    for (int k = 0; k < 9; k++) iv[k] = okm[k] ? ip[offs[k]] : 0.f;
    const float* wp = w + ((size_t)co0 * CI + ci) * 9;
#pragma unroll
    for (int cg = 0; cg < COT; cg++) {
      const float* wc = wp + (size_t)cg * CI * 9;
#pragma unroll
      for (int k = 0; k < 9; k++) acc[cg] = fmaf(iv[k], wc[k], acc[cg]);
    }
  }

  float* ob = out + (size_t)b * out_bs + (size_t)rem;
#pragma unroll
  for (int cg = 0; cg < COT; cg++) {
    float v = acc[cg] * s[co0 + cg] + t[co0 + cg];
    ob[(size_t)(co0 + cg) * HW] = fmaxf(v, 0.f);
  }
}

extern "C" void kernel_launch(void* const* d_in, const int* in_sizes, int n_in,
                              void* d_out, int out_size, void* d_ws, size_t ws_size,
                              hipStream_t stream) {
  const float* pts  = (const float*)d_in[0];
  const float* vw   = (const float*)d_in[1];
  const float* vs   = (const float*)d_in[2];
  const float* vt   = (const float*)d_in[3];
  const float* b1w0 = (const float*)d_in[4];
  const float* b1s0 = (const float*)d_in[5];
  const float* b1t0 = (const float*)d_in[6];
  const float* b1w  = (const float*)d_in[7];
  const float* b1s  = (const float*)d_in[8];
  const float* b1t  = (const float*)d_in[9];
  const float* b2w0 = (const float*)d_in[10];
  const float* b2s0 = (const float*)d_in[11];
  const float* b2t0 = (const float*)d_in[12];
  const float* b2w  = (const float*)d_in[13];
  const float* b2s  = (const float*)d_in[14];
  const float* b2t  = (const float*)d_in[15];
  const float* b3w0 = (const float*)d_in[16];
  const float* b3s0 = (const float*)d_in[17];
  const float* b3t0 = (const float*)d_in[18];
  const float* b3w  = (const float*)d_in[19];
  const float* b3s  = (const float*)d_in[20];
  const float* b3t  = (const float*)d_in[21];
  float* out = (float*)d_out;

  // --- workspace: ONLY 64*HW floats (54.9 MB), aliased lifetimes (see R5) ---
  float* wsf = (float*)d_ws;
  int* cnt = (int*)wsf;                       // [0, 2HW) as ints
  float* sums = wsf + (size_t)2 * HW;         // [2HW, 8HW)
  float* s16a = wsf;                          // [0, 32HW)
  float* s16b = wsf + (size_t)32 * HW;        // [32HW, 64HW)
  float* p64 = wsf;                           // [0, 64HW)

  // canvas = out channels 20..83, both batches (harness poisons d_out -> clear it)
  hipMemsetAsync(out + (size_t)20 * HW, 0, (size_t)64 * HW * sizeof(float), stream);
  hipMemsetAsync(out + (size_t)(84 + 20) * HW, 0, (size_t)64 * HW * sizeof(float),
                 stream);
  hipMemsetAsync(cnt, 0, (size_t)8 * HW * sizeof(float), stream);  // cnt + sums

  count_kernel<<<(Bn * Np + 255) / 256, 256, 0, stream>>>(pts, cnt, sums);
  vfe_kernel<<<(Bn * Np * 64 + 255) / 256, 256, 0, stream>>>(pts, cnt, sums, vw, vs,
                                                             vt, out);

  const int g2 = (2 * HW + 255) / 256;  // both batches
  const int g1 = (HW + 255) / 256;      // one batch
  dim3 blk(256);
  float* canvas = out + (size_t)20 * HW;  // batch stride 84*HW

  // block1: 64->4, then 3x (4->4); x1 -> out channels 0..3
  conv3x3<64, 4><<<dim3(g2, 1), blk, 0, stream>>>(canvas, 84 * HW, b1w0, b1s0, b1t0,
                                                  s16a, 4 * HW, 2 * HW);
  conv3x3<4, 4><<<dim3(g2, 1), blk, 0, stream>>>(s16a, 4 * HW, b1w + 0 * 144,
                                                 b1s + 0, b1t + 0, s16b, 4 * HW,
                                                 2 * HW);
  conv3x3<4, 4><<<dim3(g2, 1), blk, 0, stream>>>(s16b, 4 * HW, b1w + 1 * 144,
                                                 b1s + 4, b1t + 4, s16a, 4 * HW,
                                                 2 * HW);
  conv3x3<4, 4><<<dim3(g2, 1), blk, 0, stream>>>(s16a, 4 * HW, b1w + 2 * 144,
                                                 b1s + 8, b1t + 8, out, 84 * HW,
                                                 2 * HW);

  // block2: 4->16, then 5x (16->16); x2 -> out channels 4..19
  conv3x3<4, 16><<<dim3(g2, 1), blk, 0, stream>>>(out, 84 * HW, b2w0, b2s0, b2t0,
                                                  s16a, 16 * HW, 2 * HW);
  conv3x3<16, 16><<<dim3(g2, 1), blk, 0, stream>>>(s16a, 16 * HW, b2w + 0 * 2304,
                                                   b2s + 0, b2t + 0, s16b, 16 * HW,
                                                   2 * HW);
  conv3x3<16, 16><<<dim3(g2, 1), blk, 0, stream>>>(s16b, 16 * HW, b2w + 1 * 2304,
                                                   b2s + 16, b2t + 16, s16a, 16 * HW,
                                                   2 * HW);
  conv3x3<16, 16><<<dim3(g2, 1), blk, 0, stream>>>(s16a, 16 * HW, b2w + 2 * 2304,
                                                   b2s + 32, b2t + 32, s16b, 16 * HW,
                                                   2 * HW);
  conv3x3<16, 16><<<dim3(g2, 1), blk, 0, stream>>>(s16b, 16 * HW, b2w + 3 * 2304,
                                                   b2s + 48, b2t + 48, s16a, 16 * HW,
                                                   2 * HW);
  conv3x3<16, 16><<<dim3(g2, 1), blk, 0, stream>>>(s16a, 16 * HW, b2w + 4 * 2304,
                                                   b2s + 64, b2t + 64, out + 4 * HW,
                                                   84 * HW, 2 * HW);

  // block3: 16->64 then 5x (64->64), PER BATCH, ping-pong p64 <-> canvas_b.
  for (int b = 0; b < Bn; b++) {
    const float* x2b = out + (size_t)b * 84 * HW + (size_t)4 * HW;
    float* cb = out + (size_t)b * 84 * HW + (size_t)20 * HW;
    conv3x3<16, 16><<<dim3(g1, 4), blk, 0, stream>>>(x2b, 0, b3w0, b3s0, b3t0, p64,
                                                     0, HW);
    conv3x3<64, 16><<<dim3(g1, 4), blk, 0, stream>>>(p64, 0, b3w + 0 * 36864,
                                                     b3s + 0, b3t + 0, cb, 0, HW);
    conv3x3<64, 16><<<dim3(g1, 4), blk, 0, stream>>>(cb, 0, b3w + 1 * 36864,
                                                     b3s + 64, b3t + 64, p64, 0, HW);
    conv3x3<64, 16><<<dim3(g1, 4), blk, 0, stream>>>(p64, 0, b3w + 2 * 36864,
                                                     b3s + 128, b3t + 128, cb, 0, HW);
    conv3x3<64, 16><<<dim3(g1, 4), blk, 0, stream>>>(cb, 0, b3w + 3 * 36864,
                                                     b3s + 192, b3t + 192, p64, 0,
                                                     HW);
    conv3x3<64, 16><<<dim3(g1, 4), blk, 0, stream>>>(p64, 0, b3w + 4 * 36864,
                                                     b3s + 256, b3t + 256, cb, 0, HW);
  }
}

// Round 9
// 1357.340 us; speedup vs baseline: 2.6342x; 2.6342x over previous
//
#include <hip/hip_runtime.h>
#include <math.h>

static constexpr int H = 496, W = 432, Bn = 2, Np = 16000;
static constexpr int HW = H * W;  // 214272

typedef __bf16 bf16x8 __attribute__((ext_vector_type(8)));
typedef float f32x16 __attribute__((ext_vector_type(16)));

// Gold-matching binning (R7-verified): multiply by f32-rounded reciprocal
// (RN_f32(1/0.16f) == 6.25f). DO NOT change to division.
__device__ inline void bin_xy(float px, float py, int& ix, int& iy) {
  ix = (int)floorf(px * 6.25f);
  iy = (int)floorf((py + 39.68f) * 6.25f);
  ix = min(max(ix, 0), W - 1);
  iy = min(max(iy, 0), H - 1);
}

// ---------------- Voxelization pass 1 ----------------
__global__ __launch_bounds__(256)
void count_kernel(const float* __restrict__ pts, int* __restrict__ cnt,
                  float* __restrict__ sums) {
  int p = blockIdx.x * blockDim.x + threadIdx.x;
  if (p >= Bn * Np) return;
  float px = pts[p * 4 + 0], py = pts[p * 4 + 1], pz = pts[p * 4 + 2];
  int b = p / Np;
  int ix, iy;
  bin_xy(px, py, ix, iy);
  int gid = b * HW + iy * W + ix;
  atomicAdd(&cnt[gid], 1);
  atomicAdd(&sums[3 * gid + 0], px);
  atomicAdd(&sums[3 * gid + 1], py);
  atomicAdd(&sums[3 * gid + 2], pz);
}

// ---------------- Voxelization pass 2: VFE + atomicMax scatter ----------------
__global__ __launch_bounds__(256)
void vfe_kernel(const float* __restrict__ pts, const int* __restrict__ cnt,
                const float* __restrict__ sums, const float* __restrict__ vw,
                const float* __restrict__ vs, const float* __restrict__ vt,
                float* __restrict__ out) {
  int tid = blockIdx.x * blockDim.x + threadIdx.x;
  if (tid >= Bn * Np * 64) return;
  int o = tid & 63;
  int p = tid >> 6;
  int b = p / Np;
  float px = pts[p * 4 + 0], py = pts[p * 4 + 1];
  float pz = pts[p * 4 + 2], pr = pts[p * 4 + 3];
  int ix, iy;
  bin_xy(px, py, ix, iy);
  int gid = b * HW + iy * W + ix;
  int n = cnt[gid];
  float denom = (float)max(n, 1);
  float mx = sums[3 * gid + 0] / denom;
  float my = sums[3 * gid + 1] / denom;
  float mz = sums[3 * gid + 2] / denom;
  float cx = (float)ix * 0.16f + 0.08f;
  float cy = (float)iy * 0.16f + (0.08f - 39.68f);
  float f[10] = {px, py, pz, pr, px - mx, py - my, pz - mz,
                 px - cx, py - cy, pz + 1.0f};
  const float* wr = vw + o * 10;
  float d = 0.f;
#pragma unroll
  for (int c = 0; c < 10; c++) d += f[c] * wr[c];
  float val = d * vs[o] + vt[o];
  val = fmaxf(val, 0.f);
  if (n < 32) val = fmaxf(val, fmaxf(vt[o], 0.f));
  unsigned int* dst = (unsigned int*)(out + (size_t)b * (84 * HW) +
                                      (size_t)(20 + o) * HW + (size_t)iy * W + ix);
  atomicMax(dst, __float_as_uint(val));
}

// ---------------- fp32 direct 3x3 conv (blocks 1 & 2 only) ----------------
template <int CI, int COT>
__global__ __launch_bounds__(256)
void conv3x3(const float* __restrict__ in, int in_bs, const float* __restrict__ w,
             const float* __restrict__ s, const float* __restrict__ t,
             float* __restrict__ out, int out_bs, int npix) {
  int pix = blockIdx.x * blockDim.x + threadIdx.x;
  if (pix >= npix) return;
  int b = pix / HW;
  int rem = pix - b * HW;
  int y = rem / W;
  int x = rem - y * W;
  int co0 = blockIdx.y * COT;
  const float* inb = in + (size_t)b * in_bs;

  int offs[9];
  bool okm[9];
#pragma unroll
  for (int ky = 0; ky < 3; ky++) {
    int yy = y + ky - 1;
    bool yok = (unsigned)yy < (unsigned)H;
#pragma unroll
    for (int kx = 0; kx < 3; kx++) {
      int xx = x + kx - 1;
      okm[ky * 3 + kx] = yok && ((unsigned)xx < (unsigned)W);
      offs[ky * 3 + kx] = yy * W + xx;
    }
  }
  float acc[COT];
#pragma unroll
  for (int i = 0; i < COT; i++) acc[i] = 0.f;
  for (int ci = 0; ci < CI; ci++) {
    const float* ip = inb + (size_t)ci * HW;
    float iv[9];
#pragma unroll
    for (int k = 0; k < 9; k++) iv[k] = okm[k] ? ip[offs[k]] : 0.f;
    const float* wp = w + ((size_t)co0 * CI + ci) * 9;
#pragma unroll
    for (int cg = 0; cg < COT; cg++) {
      const float* wc = wp + (size_t)cg * CI * 9;
#pragma unroll
      for (int k = 0; k < 9; k++) acc[cg] = fmaf(iv[k], wc[k], acc[cg]);
    }
  }
  float* ob = out + (size_t)b * out_bs + (size_t)rem;
#pragma unroll
  for (int cg = 0; cg < COT; cg++) {
    float v = acc[cg] * s[co0 + cg] + t[co0 + cg];
    ob[(size_t)(co0 + cg) * HW] = fmaxf(v, 0.f);
  }
}

// ---------------- weight prepack for block3: OIHW fp32 -> [co][tap][ci] bf16 ----
__global__ __launch_bounds__(256)
void prepack(const float* __restrict__ w0, const float* __restrict__ ws,
             __bf16* __restrict__ wt) {
  int idx = blockIdx.x * 256 + threadIdx.x;
  const int E0 = 64 * 144, EN = 64 * 576;
  if (idx < E0) {
    int co = idx / 144, k = idx - co * 144;
    int tp = k / 16, ci = k - tp * 16;
    int ky = tp / 3, kx = tp - ky * 3;
    wt[idx] = (__bf16)w0[((co * 16 + ci) * 3 + ky) * 3 + kx];
  } else {
    int j = idx - E0;
    if (j >= 5 * EN) return;
    int n = j / EN, rr = j - n * EN;
    int co = rr / 576, k = rr - co * 576;
    int tp = k / 64, ci = k - tp * 64;
    int ky = tp / 3, kx = tp - ky * 3;
    wt[idx] = (__bf16)ws[n * 36864 + ((co * 64 + ci) * 3 + ky) * 3 + kx];
  }
}

// ---------------- x2 (NCHW fp32, one batch) -> NHWC bf16 ----------------
__global__ __launch_bounds__(256)
void cvt_nhwc16(const float* __restrict__ x2b, __bf16* __restrict__ n16) {
  int idx = blockIdx.x * 256 + threadIdx.x;
  if (idx >= 16 * HW) return;
  int ci = idx / HW;
  int p = idx - ci * HW;
  n16[(size_t)p * 16 + ci] = (__bf16)x2b[(size_t)ci * HW + p];
}

// ---------------- MFMA implicit-GEMM 3x3 conv, NHWC bf16 in, one batch ---------
// wg = 256 thr (4 waves), tile 8x16 pixels x 64 co. Halo (10x18 x CI) staged once
// in LDS (serves all 9 taps). Wave wv computes tile rows 2wv..2wv+1 (32 px) x 64 co
// via 2 n-tiles sharing each A-frag. mfma_f32_32x32x16_bf16; fp32 accumulate.
// FINAL: BN+ReLU then LDS-transpose -> coalesced NCHW fp32 stores.
template <int CI, bool FINAL>
__global__ __launch_bounds__(256)
void mconv(const __bf16* __restrict__ in, const __bf16* __restrict__ wt,
           const float* __restrict__ s, const float* __restrict__ t,
           __bf16* __restrict__ outb, float* __restrict__ outf) {
  constexpr int K9 = 9 * CI;
  constexpr int PADW = (CI == 64) ? 72 : 24;  // bf16 per-pixel stride; 16B-aligned
  constexpr int HALO_B = 180 * PADW * 2;
  constexpr int TRAN_B = FINAL ? 128 * 66 * 4 : 0;
  constexpr int SMEM_B = HALO_B > TRAN_B ? HALO_B : TRAN_B;
  __shared__ __align__(16) char smem[SMEM_B];
  __bf16* hl = (__bf16*)smem;

  const int tid = threadIdx.x;
  const int ty = blockIdx.x / 27, tx = blockIdx.x - ty * 27;
  const int y0 = ty * 8, x0 = tx * 16;

  // stage halo: 10x18 pixels x CI channels (zeros outside image)
  constexpr int NCH = CI / 8;
  constexpr int TOT = 180 * NCH;
  for (int q = tid; q < TOT; q += 256) {
    int hp = q / NCH, c8 = q - hp * NCH;
    int hy = hp / 18, hx = hp - hy * 18;
    int gy = y0 - 1 + hy, gx = x0 - 1 + hx;
    int4 v = {0, 0, 0, 0};
    if ((unsigned)gy < (unsigned)H && (unsigned)gx < (unsigned)W)
      v = *(const int4*)(in + (size_t)(gy * W + gx) * CI + c8 * 8);
    *(int4*)(hl + hp * PADW + c8 * 8) = v;
  }
  __syncthreads();

  const int lane = tid & 63;
  const int wv = tid >> 6;
  const int col = lane & 31, half = lane >> 5;
  const int ly = wv * 2 + (col >> 4);  // A: m = col -> pixel (ly, lx) of tile
  const int lx = col & 15;

  f32x16 acc0 = {0.f, 0.f, 0.f, 0.f, 0.f, 0.f, 0.f, 0.f,
                 0.f, 0.f, 0.f, 0.f, 0.f, 0.f, 0.f, 0.f};
  f32x16 acc1 = acc0;

  const __bf16* wr0 = wt + (size_t)col * K9 + half * 8;         // co = col
  const __bf16* wr1 = wt + (size_t)(col + 32) * K9 + half * 8;  // co = col+32

#pragma unroll
  for (int tp = 0; tp < 9; ++tp) {
    const __bf16* arow = hl + ((ly + tp / 3) * 18 + lx + tp % 3) * PADW + half * 8;
    const __bf16* w0p = wr0 + tp * CI;
    const __bf16* w1p = wr1 + tp * CI;
#pragma unroll
    for (int c = 0; c < CI; c += 16) {
      bf16x8 a = *(const bf16x8*)(arow + c);
      bf16x8 b0 = *(const bf16x8*)(w0p + c);
      bf16x8 b1 = *(const bf16x8*)(w1p + c);
      acc0 = __builtin_amdgcn_mfma_f32_32x32x16_bf16(a, b0, acc0, 0, 0, 0);
      acc1 = __builtin_amdgcn_mfma_f32_32x32x16_bf16(a, b1, acc1, 0, 0, 0);
    }
  }

  float s0 = s[col], t0v = t[col], s1 = s[col + 32], t1v = t[col + 32];
  if constexpr (!FINAL) {
#pragma unroll
    for (int r = 0; r < 16; ++r) {
      int row = (r & 3) + 8 * (r >> 2) + 4 * half;  // verified C/D map (m74/m101)
      int py = y0 + wv * 2 + (row >> 4);
      int px = x0 + (row & 15);
      size_t gp = (size_t)py * W + px;
      outb[gp * 64 + col] = (__bf16)fmaxf(acc0[r] * s0 + t0v, 0.f);
      outb[gp * 64 + col + 32] = (__bf16)fmaxf(acc1[r] * s1 + t1v, 0.f);
    }
  } else {
    float* tl = (float*)smem;
    __syncthreads();  // all waves done with halo LDS
#pragma unroll
    for (int r = 0; r < 16; ++r) {
      int row = (r & 3) + 8 * (r >> 2) + 4 * half;
      int mt = wv * 32 + row;  // pixel index within 8x16 tile
      tl[mt * 66 + col] = fmaxf(acc0[r] * s0 + t0v, 0.f);
      tl[mt * 66 + col + 32] = fmaxf(acc1[r] * s1 + t1v, 0.f);
    }
    __syncthreads();
    for (int e = tid; e < 128 * 64; e += 256) {
      int co = e >> 7, mt = e & 127;
      outf[(size_t)co * HW + (size_t)(y0 + (mt >> 4)) * W + x0 + (mt & 15)] =
          tl[mt * 66 + co];
    }
  }
}

extern "C" void kernel_launch(void* const* d_in, const int* in_sizes, int n_in,
                              void* d_out, int out_size, void* d_ws, size_t ws_size,
                              hipStream_t stream) {
  const float* pts  = (const float*)d_in[0];
  const float* vw   = (const float*)d_in[1];
  const float* vs   = (const float*)d_in[2];
  const float* vt   = (const float*)d_in[3];
  const float* b1w0 = (const float*)d_in[4];
  const float* b1s0 = (const float*)d_in[5];
  const float* b1t0 = (const float*)d_in[6];
  const float* b1w  = (const float*)d_in[7];
  const float* b1s  = (const float*)d_in[8];
  const float* b1t  = (const float*)d_in[9];
  const float* b2w0 = (const float*)d_in[10];
  const float* b2s0 = (const float*)d_in[11];
  const float* b2t0 = (const float*)d_in[12];
  const float* b2w  = (const float*)d_in[13];
  const float* b2s  = (const float*)d_in[14];
  const float* b2t  = (const float*)d_in[15];
  const float* b3w0 = (const float*)d_in[16];
  const float* b3s0 = (const float*)d_in[17];
  const float* b3t0 = (const float*)d_in[18];
  const float* b3w  = (const float*)d_in[19];
  const float* b3s  = (const float*)d_in[20];
  const float* b3t  = (const float*)d_in[21];
  float* out = (float*)d_out;

  // ws usage (peak = 64*HW floats = 54.85 MB, EXACTLY the R7-proven footprint):
  //  phase vox:     cnt [0,2HW) ints + sums [2HW,8HW) floats
  //  phase blk1/2:  s16a [0,32HW) + s16b [32HW,64HW) floats
  //  phase blk3:    ppA bf16 [0, HW*64 elems = 27.4MB) ; Wt bf16 at byte 32*HW*4
  //                 (387 KB, written by prepack AFTER block2's last s16b use)
  float* wsf = (float*)d_ws;
  int* cnt = (int*)wsf;
  float* sums = wsf + (size_t)2 * HW;
  float* s16a = wsf;
  float* s16b = wsf + (size_t)32 * HW;
  __bf16* ppA = (__bf16*)d_ws;
  __bf16* Wt = (__bf16*)((char*)d_ws + (size_t)32 * HW * 4);

  hipMemsetAsync(out + (size_t)20 * HW, 0, (size_t)64 * HW * sizeof(float), stream);
  hipMemsetAsync(out + (size_t)(84 + 20) * HW, 0, (size_t)64 * HW * sizeof(float),
                 stream);
  hipMemsetAsync(cnt, 0, (size_t)8 * HW * sizeof(float), stream);

  count_kernel<<<(Bn * Np + 255) / 256, 256, 0, stream>>>(pts, cnt, sums);
  vfe_kernel<<<(Bn * Np * 64 + 255) / 256, 256, 0, stream>>>(pts, cnt, sums, vw, vs,
                                                             vt, out);

  const int g2 = (2 * HW + 255) / 256;
  dim3 blk(256);
  float* canvas = out + (size_t)20 * HW;

  // block1: 64->4, 3x(4->4); x1 -> out ch0..3
  conv3x3<64, 4><<<dim3(g2, 1), blk, 0, stream>>>(canvas, 84 * HW, b1w0, b1s0, b1t0,
                                                  s16a, 4 * HW, 2 * HW);
  conv3x3<4, 4><<<dim3(g2, 1), blk, 0, stream>>>(s16a, 4 * HW, b1w + 0 * 144,
                                                 b1s + 0, b1t + 0, s16b, 4 * HW,
                                                 2 * HW);
  conv3x3<4, 4><<<dim3(g2, 1), blk, 0, stream>>>(s16b, 4 * HW, b1w + 1 * 144,
                                                 b1s + 4, b1t + 4, s16a, 4 * HW,
                                                 2 * HW);
  conv3x3<4, 4><<<dim3(g2, 1), blk, 0, stream>>>(s16a, 4 * HW, b1w + 2 * 144,
                                                 b1s + 8, b1t + 8, out, 84 * HW,
                                                 2 * HW);

  // block2: 4->16, 5x(16->16); x2 -> out ch4..19
  conv3x3<4, 16><<<dim3(g2, 1), blk, 0, stream>>>(out, 84 * HW, b2w0, b2s0, b2t0,
                                                  s16a, 16 * HW, 2 * HW);
  conv3x3<16, 16><<<dim3(g2, 1), blk, 0, stream>>>(s16a, 16 * HW, b2w + 0 * 2304,
                                                   b2s + 0, b2t + 0, s16b, 16 * HW,
                                                   2 * HW);
  conv3x3<16, 16><<<dim3(g2, 1), blk, 0, stream>>>(s16b, 16 * HW, b2w + 1 * 2304,
                                                   b2s + 16, b2t + 16, s16a, 16 * HW,
                                                   2 * HW);
  conv3x3<16, 16><<<dim3(g2, 1), blk, 0, stream>>>(s16a, 16 * HW, b2w + 2 * 2304,
                                                   b2s + 32, b2t + 32, s16b, 16 * HW,
                                                   2 * HW);
  conv3x3<16, 16><<<dim3(g2, 1), blk, 0, stream>>>(s16b, 16 * HW, b2w + 3 * 2304,
                                                   b2s + 48, b2t + 48, s16a, 16 * HW,
                                                   2 * HW);
  conv3x3<16, 16><<<dim3(g2, 1), blk, 0, stream>>>(s16a, 16 * HW, b2w + 4 * 2304,
                                                   b2s + 64, b2t + 64, out + 4 * HW,
                                                   84 * HW, 2 * HW);

  // prepack AFTER block2 (s16a/s16b dead from here on)
  prepack<<<756, 256, 0, stream>>>(b3w0, b3w, Wt);

  // block3 via MFMA, per batch. pong_b = out ch20..83 of batch b reused as raw
  // bf16 storage (dead since block1-conv0; FINAL rewrites it as x3 fp32).
  dim3 mg(62 * 27, 1);
  for (int b = 0; b < Bn; b++) {
    const float* x2b = out + (size_t)b * 84 * HW + (size_t)4 * HW;
    float* cb = out + (size_t)b * 84 * HW + (size_t)20 * HW;
    __bf16* pong = (__bf16*)cb;
    __bf16* n16 = (__bf16*)cb;  // n16 dead before pong first written (L1)
    cvt_nhwc16<<<(16 * HW + 255) / 256, 256, 0, stream>>>(x2b, n16);
    mconv<16, false><<<mg, blk, 0, stream>>>(n16, Wt, b3s0, b3t0, ppA, nullptr);
    mconv<64, false><<<mg, blk, 0, stream>>>(ppA, Wt + 9216 + 0 * 36864, b3s + 0,
                                             b3t + 0, pong, nullptr);
    mconv<64, false><<<mg, blk, 0, stream>>>(pong, Wt + 9216 + 1 * 36864, b3s + 64,
                                             b3t + 64, ppA, nullptr);
    mconv<64, false><<<mg, blk, 0, stream>>>(ppA, Wt + 9216 + 2 * 36864, b3s + 128,
                                             b3t + 128, pong, nullptr);
    mconv<64, false><<<mg, blk, 0, stream>>>(pong, Wt + 9216 + 3 * 36864, b3s + 192,
                                             b3t + 192, ppA, nullptr);
    mconv<64, true><<<mg, blk, 0, stream>>>(ppA, Wt + 9216 + 4 * 36864, b3s + 256,
                                            b3t + 256, nullptr, cb);
  }
}